// Round 2
// baseline (180.478 us; speedup 1.0000x reference)
//
#include <hip/hip_runtime.h>

#define DEG 32
#define HID 32
#define CIN 8

// gelu(x) = 0.5x(1+tanh(sqrt(2/pi)(x + 0.044715 x^3)))   [jax approximate=True]
//         = x - x * rcp(1 + exp2( x*(A + B*x^2) ))
// A = 2*log2(e)*sqrt(2/pi), B = A*0.044715
__device__ __forceinline__ float gelu_tanh(float x) {
    constexpr float A = (float)(2.0 * 1.4426950408889634 * 0.7978845608028654);
    constexpr float B = (float)(2.0 * 1.4426950408889634 * 0.7978845608028654 * 0.044715);
    float x2 = x * x;
    float z  = x * fmaf(B, x2, A);
    float e  = __builtin_amdgcn_exp2f(z);
    float r  = __builtin_amdgcn_rcpf(1.0f + e);
    return fmaf(-x, r, x);   // x->-inf: r->1 => 0.  x->+inf: r->0 => x.
}

// Single fused kernel. Block = 256 threads = 4 waves = 8 nodes (one node per
// half-wave; lane%32 = hidden channel). Per node:
//   v_i[h]  = b1[h] + x_i @ W1[8:]          (preamble, 8 FMA)
//   g[h]    = sum_j w_j * gelu(x_j@W1[:8][h] + v_i[h])   (32-iter inner loop)
//   out[h]  = (g @ W2 + (sum_j w_j)*b2[h]) / 32
// x-table is 3.2 MB -> L2-resident, so the random x_j gather never hits HBM.
__global__ __launch_bounds__(256) void fused_git(
    const float* __restrict__ x, const float* __restrict__ wgt,
    const float* __restrict__ W1, const float* __restrict__ b1,
    const float* __restrict__ W2, const float* __restrict__ b2,
    const int* __restrict__ nbr, float* __restrict__ out, int N) {
    __shared__ float sW2[HID * HID];
    __shared__ float sb2[HID];
    __shared__ int2  sp[8 * DEG];     // per node-slot: (j*32 byte-offset, w_j bits)

    int t = threadIdx.x;
#pragma unroll
    for (int i = 0; i < 4; ++i) sW2[t + i * 256] = W2[t + i * 256];
    if (t < HID) sb2[t] = b2[t];

    int slot = t >> 5;                 // 0..7 node slot within block
    int hid  = t & 31;
    int node = blockIdx.x * 8 + slot;
    bool valid = node < N;
    int nclamp = valid ? node : (N - 1);   // keep loads in-bounds, guard stores

    // stage this node's neighbor (byte-offset, weight) pairs into LDS
    int   j_own = nbr[nclamp * DEG + hid];          // coalesced 128B per half
    float w_own = wgt[j_own];                       // tiny-table gather
    sp[slot * DEG + hid] = make_int2(j_own * (CIN * 4), __float_as_int(w_own));

    // self part: v = b1 + x_i @ W1[8:16]
    const float4* xip = (const float4*)(x + (size_t)nclamp * CIN);
    float4 xa = xip[0], xb2v = xip[1];
    float w1t[8];
#pragma unroll
    for (int k = 0; k < 8; ++k) w1t[k] = W1[k * HID + hid];
    float vb = b1[hid];
    vb = fmaf(xa.x,   W1[ 8 * HID + hid], vb);
    vb = fmaf(xa.y,   W1[ 9 * HID + hid], vb);
    vb = fmaf(xa.z,   W1[10 * HID + hid], vb);
    vb = fmaf(xa.w,   W1[11 * HID + hid], vb);
    vb = fmaf(xb2v.x, W1[12 * HID + hid], vb);
    vb = fmaf(xb2v.y, W1[13 * HID + hid], vb);
    vb = fmaf(xb2v.z, W1[14 * HID + hid], vb);
    vb = fmaf(xb2v.w, W1[15 * HID + hid], vb);

    __syncthreads();

    // ws = sum of the 32 neighbor weights (butterfly within the half-wave)
    float ws = w_own;
    ws += __shfl_xor(ws, 1);
    ws += __shfl_xor(ws, 2);
    ws += __shfl_xor(ws, 4);
    ws += __shfl_xor(ws, 8);
    ws += __shfl_xor(ws, 16);

    const char* xbytes = (const char*)x;
    const int2* myp = &sp[slot * DEG];
    float g = 0.f;
#pragma unroll 8
    for (int e = 0; e < DEG; ++e) {
        int2  p  = myp[e];                   // ds_read_b64, broadcast (uniform per half)
        float wj = __int_as_float(p.y);
        const float4* xjp = (const float4*)(xbytes + (unsigned)p.x);
        float4 a = xjp[0], b = xjp[1];       // 2x dwordx4, L2-resident gather
        float tin = vb;
        tin = fmaf(a.x, w1t[0], tin);
        tin = fmaf(a.y, w1t[1], tin);
        tin = fmaf(a.z, w1t[2], tin);
        tin = fmaf(a.w, w1t[3], tin);
        tin = fmaf(b.x, w1t[4], tin);
        tin = fmaf(b.y, w1t[5], tin);
        tin = fmaf(b.z, w1t[6], tin);
        tin = fmaf(b.w, w1t[7], tin);
        g = fmaf(wj, gelu_tanh(tin), g);
    }

    // second linear hoisted per node: out = (g @ W2 + ws*b2) / DEG
    float acc = 0.f;
#pragma unroll
    for (int h = 0; h < HID; ++h) {
        float gh = __shfl(g, h, 32);         // broadcast within the half-wave
        acc = fmaf(gh, sW2[h * HID + hid], acc);
    }
    if (valid) {
        out[(size_t)node * HID + hid] = fmaf(ws, sb2[hid], acc) * (1.0f / DEG);
    }
}

extern "C" void kernel_launch(void* const* d_in, const int* in_sizes, int n_in,
                              void* d_out, int out_size, void* d_ws, size_t ws_size,
                              hipStream_t stream) {
    const float* x   = (const float*)d_in[0];
    const float* wq  = (const float*)d_in[1];
    const float* W1  = (const float*)d_in[2];
    const float* b1  = (const float*)d_in[3];
    const float* W2  = (const float*)d_in[4];
    const float* b2  = (const float*)d_in[5];
    const int*   nbr = (const int*)d_in[6];
    float* out = (float*)d_out;

    int N = in_sizes[1];                 // in_weights has N elements
    int blocks = (N + 7) / 8;            // 8 nodes per 256-thread block
    fused_git<<<blocks, 256, 0, stream>>>(x, wq, W1, b1, W2, b2, nbr, out, N);
}

// Round 3
// 135.238 us; speedup vs baseline: 1.3345x; 1.3345x over previous
//
#include <hip/hip_runtime.h>

#define DEG 32
#define HID 32
#define CIN 8

// gelu(x) = 0.5x(1+tanh(sqrt(2/pi)(x + 0.044715 x^3)))   [jax approximate=True]
//         = x - x * rcp(1 + exp2( x*(A + B*x^2) ))
__device__ __forceinline__ float gelu_tanh(float x) {
    constexpr float A = (float)(2.0 * 1.4426950408889634 * 0.7978845608028654);
    constexpr float B = (float)(2.0 * 1.4426950408889634 * 0.7978845608028654 * 0.044715);
    float x2 = x * x;
    float z  = x * fmaf(B, x2, A);
    float e  = __builtin_amdgcn_exp2f(z);
    float r  = __builtin_amdgcn_rcpf(1.0f + e);
    return fmaf(-x, r, x);   // x->-inf: r->1 => 0.  x->+inf: r->0 => x.
}

// Phase 1: u[n][h] = x[n] @ W1[:8][h]. Thread per (node, 4 channels):
// W1 reads are dwordx4-coalesced, store is float4-coalesced, x row is an
// 8-thread broadcast. ~800k threads, trivial.
__global__ __launch_bounds__(256) void precompute_u(
    const float* __restrict__ x, const float* __restrict__ W1,
    float* __restrict__ u, int N) {
    int tid = blockIdx.x * 256 + threadIdx.x;
    if (tid >= N * (HID / 4)) return;
    int n  = tid >> 3;
    int hq = tid & 7;                       // which float4 of the 32-wide row
    const float4* xp = (const float4*)(x + (size_t)n * CIN);
    float4 a = xp[0], b = xp[1];
    float xv[8] = {a.x, a.y, a.z, a.w, b.x, b.y, b.z, b.w};
    float4 s = make_float4(0.f, 0.f, 0.f, 0.f);
#pragma unroll
    for (int k = 0; k < 8; ++k) {
        float4 wrow = *(const float4*)(W1 + k * HID + hq * 4);
        s.x = fmaf(xv[k], wrow.x, s.x);
        s.y = fmaf(xv[k], wrow.y, s.y);
        s.z = fmaf(xv[k], wrow.z, s.z);
        s.w = fmaf(xv[k], wrow.w, s.w);
    }
    *(float4*)(u + (size_t)n * HID + hq * 4) = s;
}

// Phase 2: half-wave per node (8 nodes / 256-thread block). lane%32 = channel.
//   v_i[h] = b1[h] + x_i @ W1[8:]                       (preamble)
//   g[h]   = sum_j w_j * gelu(u_j[h] + v_i[h])          (32-iter gather loop)
//   out[h] = (g @ W2 + (sum_j w_j)*b2[h]) / 32          (hoisted 2nd linear)
__global__ __launch_bounds__(256) void git_main(
    const float* __restrict__ u, const float* __restrict__ x,
    const float* __restrict__ wgt, const float* __restrict__ W1,
    const float* __restrict__ b1, const float* __restrict__ W2,
    const float* __restrict__ b2, const int* __restrict__ nbr,
    float* __restrict__ out, int N) {
    __shared__ float sW2[HID * HID];
    __shared__ float sb2[HID];
    __shared__ int2  sp[8 * DEG];      // per node-slot: (j*128 byte-offset, w_j bits)

    int t = threadIdx.x;
#pragma unroll
    for (int i = 0; i < 4; ++i) sW2[t + i * 256] = W2[t + i * 256];
    if (t < HID) sb2[t] = b2[t];

    int slot = t >> 5;                 // 0..7 node slot
    int hid  = t & 31;
    int node = blockIdx.x * 8 + slot;
    bool valid = node < N;
    int nc = valid ? node : (N - 1);

    // stage this node's (u-row byte offset, weight) pairs
    int   j_own = nbr[nc * DEG + hid];             // coalesced 128B per half
    float w_own = wgt[j_own];                      // 400KB table, L2-hot
    sp[slot * DEG + hid] = make_int2(j_own * (HID * 4), __float_as_int(w_own));

    // v = b1 + x_i @ W1[8:16]  (W1 col loads coalesced across hid, L2-hot)
    const float4* xip = (const float4*)(x + (size_t)nc * CIN);
    float4 xa = xip[0], xb = xip[1];
    float vb = b1[hid];
    vb = fmaf(xa.x, W1[ 8 * HID + hid], vb);
    vb = fmaf(xa.y, W1[ 9 * HID + hid], vb);
    vb = fmaf(xa.z, W1[10 * HID + hid], vb);
    vb = fmaf(xa.w, W1[11 * HID + hid], vb);
    vb = fmaf(xb.x, W1[12 * HID + hid], vb);
    vb = fmaf(xb.y, W1[13 * HID + hid], vb);
    vb = fmaf(xb.z, W1[14 * HID + hid], vb);
    vb = fmaf(xb.w, W1[15 * HID + hid], vb);

    // ws = sum of neighbor weights (butterfly stays within the half-wave)
    float ws = w_own;
    ws += __shfl_xor(ws, 1);
    ws += __shfl_xor(ws, 2);
    ws += __shfl_xor(ws, 4);
    ws += __shfl_xor(ws, 8);
    ws += __shfl_xor(ws, 16);

    __syncthreads();

    const char* ub = (const char*)u;
    const int2* myp = &sp[slot * DEG];
    int hid4 = hid * 4;
    float g = 0.f;
#pragma unroll
    for (int e = 0; e < DEG; ++e) {
        int2  p  = myp[e];             // ds_read_b64 broadcast (2-way = free)
        float uj = *(const float*)(ub + (unsigned)(p.x + hid4));  // saddr+voffset
        g = fmaf(__int_as_float(p.y), gelu_tanh(uj + vb), g);
    }

    // second linear, hoisted per node
    float acc = 0.f;
#pragma unroll
    for (int h = 0; h < HID; ++h) {
        float gh = __shfl(g, h, 32);   // broadcast within half-wave
        acc = fmaf(gh, sW2[h * HID + hid], acc);  // bank=hid per lane: conflict-free
    }
    if (valid) {
        out[(size_t)node * HID + hid] = fmaf(ws, sb2[hid], acc) * (1.0f / DEG);
    }
}

// Fallback if d_ws can't hold u (needs N*HID*4 bytes): round-2 single kernel.
__global__ __launch_bounds__(256) void fused_fallback(
    const float* __restrict__ x, const float* __restrict__ wgt,
    const float* __restrict__ W1, const float* __restrict__ b1,
    const float* __restrict__ W2, const float* __restrict__ b2,
    const int* __restrict__ nbr, float* __restrict__ out, int N) {
    __shared__ float sW2[HID * HID];
    __shared__ float sb2[HID];
    __shared__ int2  sp[8 * DEG];
    int t = threadIdx.x;
#pragma unroll
    for (int i = 0; i < 4; ++i) sW2[t + i * 256] = W2[t + i * 256];
    if (t < HID) sb2[t] = b2[t];
    int slot = t >> 5, hid = t & 31;
    int node = blockIdx.x * 8 + slot;
    bool valid = node < N;
    int nc = valid ? node : (N - 1);
    int   j_own = nbr[nc * DEG + hid];
    float w_own = wgt[j_own];
    sp[slot * DEG + hid] = make_int2(j_own * (CIN * 4), __float_as_int(w_own));
    const float4* xip = (const float4*)(x + (size_t)nc * CIN);
    float4 xa = xip[0], xb = xip[1];
    float w1t[8];
#pragma unroll
    for (int k = 0; k < 8; ++k) w1t[k] = W1[k * HID + hid];
    float vb = b1[hid];
    vb = fmaf(xa.x, W1[ 8 * HID + hid], vb);
    vb = fmaf(xa.y, W1[ 9 * HID + hid], vb);
    vb = fmaf(xa.z, W1[10 * HID + hid], vb);
    vb = fmaf(xa.w, W1[11 * HID + hid], vb);
    vb = fmaf(xb.x, W1[12 * HID + hid], vb);
    vb = fmaf(xb.y, W1[13 * HID + hid], vb);
    vb = fmaf(xb.z, W1[14 * HID + hid], vb);
    vb = fmaf(xb.w, W1[15 * HID + hid], vb);
    float ws = w_own;
    ws += __shfl_xor(ws, 1);  ws += __shfl_xor(ws, 2);
    ws += __shfl_xor(ws, 4);  ws += __shfl_xor(ws, 8);
    ws += __shfl_xor(ws, 16);
    __syncthreads();
    const char* xbytes = (const char*)x;
    const int2* myp = &sp[slot * DEG];
    float g = 0.f;
#pragma unroll 8
    for (int e = 0; e < DEG; ++e) {
        int2  p  = myp[e];
        float wj = __int_as_float(p.y);
        const float4* xjp = (const float4*)(xbytes + (unsigned)p.x);
        float4 a = xjp[0], b = xjp[1];
        float tin = vb;
        tin = fmaf(a.x, w1t[0], tin); tin = fmaf(a.y, w1t[1], tin);
        tin = fmaf(a.z, w1t[2], tin); tin = fmaf(a.w, w1t[3], tin);
        tin = fmaf(b.x, w1t[4], tin); tin = fmaf(b.y, w1t[5], tin);
        tin = fmaf(b.z, w1t[6], tin); tin = fmaf(b.w, w1t[7], tin);
        g = fmaf(wj, gelu_tanh(tin), g);
    }
    float acc = 0.f;
#pragma unroll
    for (int h = 0; h < HID; ++h) {
        float gh = __shfl(g, h, 32);
        acc = fmaf(gh, sW2[h * HID + hid], acc);
    }
    if (valid) out[(size_t)node * HID + hid] = fmaf(ws, sb2[hid], acc) * (1.0f / DEG);
}

extern "C" void kernel_launch(void* const* d_in, const int* in_sizes, int n_in,
                              void* d_out, int out_size, void* d_ws, size_t ws_size,
                              hipStream_t stream) {
    const float* x   = (const float*)d_in[0];
    const float* wq  = (const float*)d_in[1];
    const float* W1  = (const float*)d_in[2];
    const float* b1  = (const float*)d_in[3];
    const float* W2  = (const float*)d_in[4];
    const float* b2  = (const float*)d_in[5];
    const int*   nbr = (const int*)d_in[6];
    float* out = (float*)d_out;

    int N = in_sizes[1];                       // in_weights has N elements
    size_t need = (size_t)N * HID * sizeof(float);
    int blocks_main = (N + 7) / 8;             // 8 nodes per 256-thread block

    if (ws_size >= need) {
        float* u = (float*)d_ws;
        int threads_pre = N * (HID / 4);
        int blocks_pre = (threads_pre + 255) / 256;
        precompute_u<<<blocks_pre, 256, 0, stream>>>(x, W1, u, N);
        git_main<<<blocks_main, 256, 0, stream>>>(u, x, wq, W1, b1, W2, b2, nbr, out, N);
    } else {
        fused_fallback<<<blocks_main, 256, 0, stream>>>(x, wq, W1, b1, W2, b2, nbr, out, N);
    }
}